// Round 1
// baseline (979.549 us; speedup 1.0000x reference)
//
#include <hip/hip_runtime.h>
#include <math.h>

// Problem constants
// B=2, H=128, W=256, MD=34, LD=32, NH=4, HD=8, SH=64, K=25, P=7, R=3,
// FF1=512, FF2=256

__device__ __forceinline__ float gelu_f(float v) {
    return 0.5f * v * (1.0f + erff(v * 0.70710678118654752440f));
}

// ---------------------------------------------------------------------------
// K1: Wc[h][f][p] = sum_k disco_w[f][k] * psi[k][h][p]   -> d_ws (128*64*49 f32)
// ---------------------------------------------------------------------------
__global__ __launch_bounds__(256) void k1_wc(
    const float* __restrict__ psi, const float* __restrict__ dw,
    float* __restrict__ wc) {
  const int h = blockIdx.x;
  for (int e = threadIdx.x; e < 64 * 49; e += 256) {
    const int f = e / 49;
    const int p = e - f * 49;
    float acc = 0.f;
#pragma unroll
    for (int k = 0; k < 25; ++k)
      acc += dw[f * 25 + k] * psi[(k * 128 + h) * 49 + p];
    wc[h * (64 * 49) + e] = acc;
  }
}

// ---------------------------------------------------------------------------
// K2: DISCO conv + head MLP + residual -> d_out[..., 0:32]; sincos copy -> [32:34]
// grid (W/32=8, H=128, B=2), block 256.
// Wave w == head n (tid>>6). Lane: d = (tid>>3)&7, wsub = tid&7, c = n*8+d.
// Each lane does 4 pixels: w = w0 + wsub + 8*i.
// ---------------------------------------------------------------------------
__global__ __launch_bounds__(256, 4) void k2_disco_head(
    const float* __restrict__ x,  const float* __restrict__ wc,
    const float* __restrict__ db, const float* __restrict__ hw1,
    const float* __restrict__ hb1,const float* __restrict__ hw2,
    const float* __restrict__ hb2,float* __restrict__ outb) {
  __shared__ float sX[7 * 32 * 40];   // [row 7][c 32][w 40(pad of 38)]  35.8 KB

  const int tid = threadIdx.x;
  const int w0  = blockIdx.x * 32;
  const int h   = blockIdx.y;
  const int b   = blockIdx.z;

  // Stage x_learn tile: rows clamp(h-3..h+3), w in [w0-3, w0+34] wrapped, c 0..31
  for (int e = tid; e < 7 * 38 * 32; e += 256) {
    const int c  = e & 31;
    const int t  = e >> 5;
    const int wl = t % 38;
    const int row = t / 38;
    int hr = h - 3 + row;
    hr = hr < 0 ? 0 : (hr > 127 ? 127 : hr);
    const int wr = (w0 - 3 + wl + 256) & 255;
    sX[(row * 32 + c) * 40 + wl] = x[((b * 128 + hr) * 256 + wr) * 34 + c];
  }
  __syncthreads();

  const int n    = __builtin_amdgcn_readfirstlane(tid >> 6);  // head, wave-uniform
  const int d    = (tid >> 3) & 7;
  const int wsub = tid & 7;
  const int c    = n * 8 + d;

  const float* __restrict__ wch = wc  + h * (64 * 49);   // block-uniform
  const float* __restrict__ w1n = hw1 + n * (64 * 32);   // wave-uniform
  const float* __restrict__ b1n = hb1 + n * 32;
  const float* __restrict__ w2n = hw2 + n * 32;
  const float  b2n = hb2[n];

  for (int i = 0; i < 4; ++i) {
    const int wl = wsub + 8 * i;

    // taps: 49 values, LDS reads are exactly 2-way bank aliased (free)
    float tap[49];
    const float* sxb = &sX[c * 40 + wl];
#pragma unroll
    for (int r = 0; r < 7; ++r)
#pragma unroll
      for (int j = 0; j < 7; ++j)
        tap[r * 7 + j] = sxb[r * 1280 + j];

    float hacc[32];
#pragma unroll
    for (int o = 0; o < 32; ++o) hacc[o] = b1n[o];

    // fused: dvec[f] never stored; immediately folded into the 32 MLP1 accs
#pragma unroll 1
    for (int f = 0; f < 64; ++f) {
      const float* __restrict__ wrow = wch + f * 49;   // uniform -> s_load
      float acc = db[f];
#pragma unroll
      for (int p = 0; p < 49; ++p) acc += wrow[p] * tap[p];
      const float* __restrict__ w1r = w1n + f * 32;    // uniform -> s_load
#pragma unroll
      for (int o = 0; o < 32; ++o) hacc[o] += acc * w1r[o];
    }

    float r2 = b2n;
#pragma unroll
    for (int o = 0; o < 32; ++o) r2 += gelu_f(hacc[o]) * w2n[o];

    // residual = x_learn[b,h,w,c] = tap[row 3, dlon 0] = tap[24]
    outb[((b * 128 + h) * 256 + (w0 + wl)) * 34 + c] = r2 + tap[24];
  }

  // sincos passthrough for this tile's 32 pixels
  if (tid < 64) {
    const int wl = tid >> 1;
    const int sc = tid & 1;
    const int idx = ((b * 128 + h) * 256 + (w0 + wl)) * 34 + 32 + sc;
    outb[idx] = x[idx];
  }
}

// ---------------------------------------------------------------------------
// K3: fused MLP 32 -> 512(gelu) -> 256(gelu) -> 32, + residual, in-place on
// d_out[..., 0:32]. 16 pixels per block, t1/t2 in LDS (~52 KB -> 3 blocks/CU).
// ---------------------------------------------------------------------------
__global__ __launch_bounds__(256, 3) void k3_mlp(
    const float* __restrict__ fw1, const float* __restrict__ fb1,
    const float* __restrict__ fw2, const float* __restrict__ fb2,
    const float* __restrict__ fw3, const float* __restrict__ fb3,
    float* __restrict__ outb) {
  __shared__ float sIn[16 * 33];    //  2.1 KB
  __shared__ float sT1[16 * 516];   // 33.0 KB
  __shared__ float sT2[16 * 260];   // 16.6 KB

  const int tid  = threadIdx.x;
  const int pix0 = blockIdx.x * 16;

  // stage x_mid (written by K2 into d_out[...,0:32])
  for (int e = tid; e < 512; e += 256) {
    const int pix = e >> 5, k = e & 31;
    sIn[pix * 33 + k] = outb[(pix0 + pix) * 34 + k];
  }
  __syncthreads();

  // ----- layer 1: t1 = gelu(in @ fw1[0:32] + fb1)  (rows 32:34 of fw1 are 0)
  {
    const int pix = tid & 15;
    const int jg  = tid >> 4;
    const int j0  = jg * 32;
    float acc1[32];
#pragma unroll
    for (int jj = 0; jj < 32; ++jj) acc1[jj] = fb1[j0 + jj];
#pragma unroll 1
    for (int k = 0; k < 32; ++k) {
      const float a = sIn[pix * 33 + k];
      const float4* wp = (const float4*)(fw1 + k * 512 + j0);
#pragma unroll
      for (int q = 0; q < 8; ++q) {
        const float4 w = wp[q];
        acc1[q * 4 + 0] += a * w.x;
        acc1[q * 4 + 1] += a * w.y;
        acc1[q * 4 + 2] += a * w.z;
        acc1[q * 4 + 3] += a * w.w;
      }
    }
#pragma unroll
    for (int q = 0; q < 8; ++q) {
      float4 v;
      v.x = gelu_f(acc1[q * 4 + 0]);
      v.y = gelu_f(acc1[q * 4 + 1]);
      v.z = gelu_f(acc1[q * 4 + 2]);
      v.w = gelu_f(acc1[q * 4 + 3]);
      *(float4*)&sT1[pix * 516 + j0 + q * 4] = v;
    }
  }
  __syncthreads();

  // ----- layer 2: t2 = gelu(t1 @ fw2 + fb2)   (the big one: K=512, N=256)
  {
    const int wave = tid >> 6;
    const int lane = tid & 63;
    const int og   = lane & 15;
    const int pg   = lane >> 4;           // 0..3
    const int ob   = wave * 64 + og * 4;  // output col base
    const int pb   = pg * 4;              // pixel base
    float acc2[4][4];
#pragma unroll
    for (int oi = 0; oi < 4; ++oi) {
      const float bv = fb2[ob + oi];
#pragma unroll
      for (int i = 0; i < 4; ++i) acc2[i][oi] = bv;
    }
#pragma unroll 1
    for (int jc = 0; jc < 128; ++jc) {
      float4 t1v[4];
#pragma unroll
      for (int i = 0; i < 4; ++i)
        t1v[i] = *(const float4*)&sT1[(pb + i) * 516 + jc * 4];
#pragma unroll
      for (int i2 = 0; i2 < 4; ++i2) {
        const float4 w = *(const float4*)(fw2 + (jc * 4 + i2) * 256 + ob);
#pragma unroll
        for (int i = 0; i < 4; ++i) {
          const float tv = ((const float*)&t1v[i])[i2];
          acc2[i][0] += tv * w.x;
          acc2[i][1] += tv * w.y;
          acc2[i][2] += tv * w.z;
          acc2[i][3] += tv * w.w;
        }
      }
    }
#pragma unroll
    for (int i = 0; i < 4; ++i) {
      float4 v;
      v.x = gelu_f(acc2[i][0]);
      v.y = gelu_f(acc2[i][1]);
      v.z = gelu_f(acc2[i][2]);
      v.w = gelu_f(acc2[i][3]);
      *(float4*)&sT2[(pb + i) * 260 + ob] = v;
    }
  }
  __syncthreads();

  // ----- layer 3: out = t2 @ fw3 + fb3 + residual
  {
    const int pix = tid & 15;
    const int oh  = tid >> 4;
    const int o2  = oh * 2;
    float a0 = fb3[o2], a1 = fb3[o2 + 1];
#pragma unroll 1
    for (int kc = 0; kc < 64; ++kc) {
      const float4 t2v = *(const float4*)&sT2[pix * 260 + kc * 4];
#pragma unroll
      for (int i2 = 0; i2 < 4; ++i2) {
        const float2 w = *(const float2*)(fw3 + (kc * 4 + i2) * 32 + o2);
        const float tv = ((const float*)&t2v)[i2];
        a0 += tv * w.x;
        a1 += tv * w.y;
      }
    }
    float2 outv;
    outv.x = a0 + sIn[pix * 33 + o2];
    outv.y = a1 + sIn[pix * 33 + o2 + 1];
    *(float2*)&outb[(pix0 + pix) * 34 + o2] = outv;
  }
}

// ---------------------------------------------------------------------------
extern "C" void kernel_launch(void* const* d_in, const int* in_sizes, int n_in,
                              void* d_out, int out_size, void* d_ws, size_t ws_size,
                              hipStream_t stream) {
  const float* x   = (const float*)d_in[0];
  const float* psi = (const float*)d_in[1];
  const float* dw  = (const float*)d_in[2];
  const float* db  = (const float*)d_in[3];
  const float* hw1 = (const float*)d_in[4];
  const float* hb1 = (const float*)d_in[5];
  const float* hw2 = (const float*)d_in[6];
  const float* hb2 = (const float*)d_in[7];
  const float* fw1 = (const float*)d_in[8];
  const float* fb1 = (const float*)d_in[9];
  const float* fw2 = (const float*)d_in[10];
  const float* fb2 = (const float*)d_in[11];
  const float* fw3 = (const float*)d_in[12];
  const float* fb3 = (const float*)d_in[13];
  float* outb = (float*)d_out;
  float* wc   = (float*)d_ws;  // 128*64*49 floats = 1.6 MB

  hipLaunchKernelGGL(k1_wc, dim3(128), dim3(256), 0, stream, psi, dw, wc);
  hipLaunchKernelGGL(k2_disco_head, dim3(8, 128, 2), dim3(256), 0, stream,
                     x, wc, db, hw1, hb1, hw2, hb2, outb);
  hipLaunchKernelGGL(k3_mlp, dim3(4096), dim3(256), 0, stream,
                     fw1, fb1, fw2, fb2, fw3, fb3, outb);
}

// Round 2
// 579.544 us; speedup vs baseline: 1.6902x; 1.6902x over previous
//
#include <hip/hip_runtime.h>
#include <math.h>

// Problem constants
// B=2, H=128, W=256, MD=34, LD=32, NH=4, HD=8, SH=64, K=25, P=7, R=3,
// FF1=512, FF2=256

typedef __attribute__((ext_vector_type(8))) short bfrag;   // 8 bf16 = 4 VGPR
typedef __attribute__((ext_vector_type(4))) float ffrag;   // 4 f32 acc

__device__ __forceinline__ float gelu_f(float v) {
    return 0.5f * v * (1.0f + erff(v * 0.70710678118654752440f));
}

__device__ __forceinline__ short f2bf(float f) {
  union { float f; unsigned u; } v; v.f = f;
  unsigned r = (v.u + 0x7fffu + ((v.u >> 16) & 1u)) >> 16;  // RNE
  return (short)r;
}

// ---------------------------------------------------------------------------
// K0: swizzle fw1/fw2/fw3 into bf16 MFMA B-fragments (fragment-major).
// B-frag layout for 16x16x32: lane holds B[k][n], n=lane&15, k=(lane>>4)*8+j.
// Storage: frag(kt,nt) at ((kt*NT+nt)*64 + lane)*8 + j.
// ---------------------------------------------------------------------------
__global__ __launch_bounds__(256) void k0_prep(
    const float* __restrict__ fw1, const float* __restrict__ fw2,
    const float* __restrict__ fw3, short* __restrict__ fw1s,
    short* __restrict__ fw2s, short* __restrict__ fw3s) {
  const int e = blockIdx.x * 256 + threadIdx.x;
  if (e < 16384) {                       // fw1: K=32 (1 kt), N=512 (32 nt)
    const int j = e & 7, lane = (e >> 3) & 63, nt = e >> 9;
    const int k = (lane >> 4) * 8 + j, n = nt * 16 + (lane & 15);
    fw1s[e] = f2bf(fw1[k * 512 + n]);
  } else if (e < 16384 + 131072) {       // fw2: K=512 (16 kt), N=256 (16 nt)
    const int e2 = e - 16384;
    const int j = e2 & 7, lane = (e2 >> 3) & 63;
    const int nt = (e2 >> 9) & 15, kt = e2 >> 13;
    const int k = kt * 32 + (lane >> 4) * 8 + j, n = nt * 16 + (lane & 15);
    fw2s[e2] = f2bf(fw2[k * 256 + n]);
  } else if (e < 16384 + 131072 + 8192) { // fw3: K=256 (8 kt), N=32 (2 nt)
    const int e3 = e - 147456;
    const int j = e3 & 7, lane = (e3 >> 3) & 63;
    const int nt = (e3 >> 9) & 1, kt = e3 >> 10;
    const int k = kt * 32 + (lane >> 4) * 8 + j, n = nt * 16 + (lane & 15);
    fw3s[e3] = f2bf(fw3[k * 32 + n]);
  }
}

// ---------------------------------------------------------------------------
// K1: Wc[h][f][p] = sum_k disco_w[f][k] * psi[k][h][p]   -> d_ws (128*64*49 f32)
// ---------------------------------------------------------------------------
__global__ __launch_bounds__(256) void k1_wc(
    const float* __restrict__ psi, const float* __restrict__ dw,
    float* __restrict__ wc) {
  const int h = blockIdx.x;
  for (int e = threadIdx.x; e < 64 * 49; e += 256) {
    const int f = e / 49;
    const int p = e - f * 49;
    float acc = 0.f;
#pragma unroll
    for (int k = 0; k < 25; ++k)
      acc += dw[f * 25 + k] * psi[(k * 128 + h) * 49 + p];
    wc[h * (64 * 49) + e] = acc;
  }
}

// ---------------------------------------------------------------------------
// K2: DISCO conv + head MLP + residual -> d_out[..., 0:32]; sincos copy -> [32:34]
// grid (W/32=8, H=128, B=2), block 256.  (unchanged from R0)
// ---------------------------------------------------------------------------
__global__ __launch_bounds__(256, 4) void k2_disco_head(
    const float* __restrict__ x,  const float* __restrict__ wc,
    const float* __restrict__ db, const float* __restrict__ hw1,
    const float* __restrict__ hb1,const float* __restrict__ hw2,
    const float* __restrict__ hb2,float* __restrict__ outb) {
  __shared__ float sX[7 * 32 * 40];   // [row 7][c 32][w 40(pad of 38)]  35.8 KB

  const int tid = threadIdx.x;
  const int w0  = blockIdx.x * 32;
  const int h   = blockIdx.y;
  const int b   = blockIdx.z;

  for (int e = tid; e < 7 * 38 * 32; e += 256) {
    const int c  = e & 31;
    const int t  = e >> 5;
    const int wl = t % 38;
    const int row = t / 38;
    int hr = h - 3 + row;
    hr = hr < 0 ? 0 : (hr > 127 ? 127 : hr);
    const int wr = (w0 - 3 + wl + 256) & 255;
    sX[(row * 32 + c) * 40 + wl] = x[((b * 128 + hr) * 256 + wr) * 34 + c];
  }
  __syncthreads();

  const int n    = __builtin_amdgcn_readfirstlane(tid >> 6);  // head, wave-uniform
  const int d    = (tid >> 3) & 7;
  const int wsub = tid & 7;
  const int c    = n * 8 + d;

  const float* __restrict__ wch = wc  + h * (64 * 49);   // block-uniform
  const float* __restrict__ w1n = hw1 + n * (64 * 32);   // wave-uniform
  const float* __restrict__ b1n = hb1 + n * 32;
  const float* __restrict__ w2n = hw2 + n * 32;
  const float  b2n = hb2[n];

  for (int i = 0; i < 4; ++i) {
    const int wl = wsub + 8 * i;

    float tap[49];
    const float* sxb = &sX[c * 40 + wl];
#pragma unroll
    for (int r = 0; r < 7; ++r)
#pragma unroll
      for (int j = 0; j < 7; ++j)
        tap[r * 7 + j] = sxb[r * 1280 + j];

    float hacc[32];
#pragma unroll
    for (int o = 0; o < 32; ++o) hacc[o] = b1n[o];

#pragma unroll 1
    for (int f = 0; f < 64; ++f) {
      const float* __restrict__ wrow = wch + f * 49;   // uniform -> s_load
      float acc = db[f];
#pragma unroll
      for (int p = 0; p < 49; ++p) acc += wrow[p] * tap[p];
      const float* __restrict__ w1r = w1n + f * 32;    // uniform -> s_load
#pragma unroll
      for (int o = 0; o < 32; ++o) hacc[o] += acc * w1r[o];
    }

    float r2 = b2n;
#pragma unroll
    for (int o = 0; o < 32; ++o) r2 += gelu_f(hacc[o]) * w2n[o];

    outb[((b * 128 + h) * 256 + (w0 + wl)) * 34 + c] = r2 + tap[24];
  }

  if (tid < 64) {
    const int wl = tid >> 1;
    const int sc = tid & 1;
    const int idx = ((b * 128 + h) * 256 + (w0 + wl)) * 34 + 32 + sc;
    outb[idx] = x[idx];
  }
}

// ---------------------------------------------------------------------------
// K3: fused MLP 32 -> 512(gelu) -> 256(gelu) -> 32 (+residual), bf16 MFMA.
// 32 pixels/block, 2048 blocks, 256 thr (4 waves). In-place on d_out[...,0:32].
// A-frag: A[m=lane&15][k=(lane>>4)*8+j]; C/D: col=lane&15, row=(lane>>4)*4+r.
// LDS: t1 32x520 bf16 (pad: row shift=4 banks -> 2-way, free), t2 32x264.
// 50 KB -> 3 blocks/CU.
// ---------------------------------------------------------------------------
__global__ __launch_bounds__(256, 3) void k3_mfma(
    const short* __restrict__ fw1s, const short* __restrict__ fw2s,
    const short* __restrict__ fw3s,
    const float* __restrict__ fb1, const float* __restrict__ fb2,
    const float* __restrict__ fb3, float* __restrict__ outb) {
  __shared__ short sT1[32 * 520];   // 33280 B
  __shared__ short sT2[32 * 264];   // 16896 B

  const int tid  = threadIdx.x;
  const int lane = tid & 63;
  const int wave = tid >> 6;
  const int pix0 = blockIdx.x * 32;
  const int lm   = lane & 15;   // m (or n) within tile
  const int lq   = lane >> 4;   // quad
  const int koff = lq * 8;

  // ---- stage A (x_mid, written by K2) as bf16 A-frags, 2 M-tiles
  bfrag aF[2];
#pragma unroll
  for (int mt = 0; mt < 2; ++mt) {
    const float* ap = outb + (pix0 + mt * 16 + lm) * 34 + koff;  // 8B aligned
    float2 v0 = *(const float2*)(ap + 0);
    float2 v1 = *(const float2*)(ap + 2);
    float2 v2 = *(const float2*)(ap + 4);
    float2 v3 = *(const float2*)(ap + 6);
    bfrag a;
    a[0] = f2bf(v0.x); a[1] = f2bf(v0.y); a[2] = f2bf(v1.x); a[3] = f2bf(v1.y);
    a[4] = f2bf(v2.x); a[5] = f2bf(v2.y); a[6] = f2bf(v3.x); a[7] = f2bf(v3.y);
    aF[mt] = a;
  }

  // ---- layer 1: t1 = gelu(x @ fw1 + fb1), K=32, N=512. wave -> 8 nTiles.
#pragma unroll
  for (int ni = 0; ni < 8; ++ni) {
    const int nt = wave * 8 + ni;
    const bfrag b = *(const bfrag*)(fw1s + nt * 512 + lane * 8);
#pragma unroll
    for (int mt = 0; mt < 2; ++mt) {
      ffrag c = {0.f, 0.f, 0.f, 0.f};
      c = __builtin_amdgcn_mfma_f32_16x16x32_bf16(aF[mt], b, c, 0, 0, 0);
      const int col = nt * 16 + lm;
      const float bias = fb1[col];
#pragma unroll
      for (int r = 0; r < 4; ++r) {
        const int row = mt * 16 + lq * 4 + r;
        sT1[row * 520 + col] = f2bf(gelu_f(c[r] + bias));
      }
    }
  }
  __syncthreads();

  // ---- layer 2: t2 = gelu(t1 @ fw2 + fb2), K=512, N=256. wave -> 4 nTiles.
  const int n0 = wave * 4;
  ffrag acc[2][4];
#pragma unroll
  for (int mt = 0; mt < 2; ++mt)
#pragma unroll
    for (int ni = 0; ni < 4; ++ni) acc[mt][ni] = ffrag{0.f, 0.f, 0.f, 0.f};

  const short* sA0 = &sT1[lm * 520 + koff];
  const short* sA1 = sA0 + 16 * 520;
  const short* w2p = fw2s + n0 * 512 + lane * 8;
#pragma unroll 4
  for (int kt = 0; kt < 16; ++kt) {
    const bfrag a0 = *(const bfrag*)(sA0 + kt * 32);
    const bfrag a1 = *(const bfrag*)(sA1 + kt * 32);
    bfrag b[4];
#pragma unroll
    for (int ni = 0; ni < 4; ++ni)
      b[ni] = *(const bfrag*)(w2p + kt * 8192 + ni * 512);
#pragma unroll
    for (int ni = 0; ni < 4; ++ni) {
      acc[0][ni] = __builtin_amdgcn_mfma_f32_16x16x32_bf16(a0, b[ni], acc[0][ni], 0, 0, 0);
      acc[1][ni] = __builtin_amdgcn_mfma_f32_16x16x32_bf16(a1, b[ni], acc[1][ni], 0, 0, 0);
    }
  }
#pragma unroll
  for (int mt = 0; mt < 2; ++mt)
#pragma unroll
    for (int ni = 0; ni < 4; ++ni) {
      const int col = (n0 + ni) * 16 + lm;
      const float bias = fb2[col];
#pragma unroll
      for (int r = 0; r < 4; ++r) {
        const int row = mt * 16 + lq * 4 + r;
        sT2[row * 264 + col] = f2bf(gelu_f(acc[mt][ni][r] + bias));
      }
    }
  __syncthreads();

  // ---- layer 3: out = t2 @ fw3 + fb3 + residual. wave -> (mTile, nTile).
  const int mt3 = wave & 1;
  const int nt3 = wave >> 1;
  ffrag c3 = {0.f, 0.f, 0.f, 0.f};
  const short* sA3 = &sT2[(mt3 * 16 + lm) * 264 + koff];
  const short* w3p = fw3s + nt3 * 512 + lane * 8;
#pragma unroll
  for (int kt = 0; kt < 8; ++kt) {
    const bfrag a = *(const bfrag*)(sA3 + kt * 32);
    const bfrag b = *(const bfrag*)(w3p + kt * 1024);
    c3 = __builtin_amdgcn_mfma_f32_16x16x32_bf16(a, b, c3, 0, 0, 0);
  }
  {
    const int col = nt3 * 16 + lm;
    const float bias = fb3[col];
#pragma unroll
    for (int r = 0; r < 4; ++r) {
      const int row = mt3 * 16 + lq * 4 + r;
      const int p = pix0 + row;
      const float res = outb[p * 34 + col];   // x_mid (unwritten so far)
      outb[p * 34 + col] = c3[r] + bias + res;
    }
  }
}

// ---------------------------------------------------------------------------
extern "C" void kernel_launch(void* const* d_in, const int* in_sizes, int n_in,
                              void* d_out, int out_size, void* d_ws, size_t ws_size,
                              hipStream_t stream) {
  const float* x   = (const float*)d_in[0];
  const float* psi = (const float*)d_in[1];
  const float* dw  = (const float*)d_in[2];
  const float* db  = (const float*)d_in[3];
  const float* hw1 = (const float*)d_in[4];
  const float* hb1 = (const float*)d_in[5];
  const float* hw2 = (const float*)d_in[6];
  const float* hb2 = (const float*)d_in[7];
  const float* fw1 = (const float*)d_in[8];
  const float* fb1 = (const float*)d_in[9];
  const float* fw2 = (const float*)d_in[10];
  const float* fb2 = (const float*)d_in[11];
  const float* fw3 = (const float*)d_in[12];
  const float* fb3 = (const float*)d_in[13];
  float* outb = (float*)d_out;

  // workspace layout
  float* wc   = (float*)d_ws;                               // 1605632 B
  short* fw1s = (short*)((char*)d_ws + 128 * 64 * 49 * 4);  // 32768 B
  short* fw2s = fw1s + 16384;                               // 262144 B
  short* fw3s = fw2s + 131072;                              // 16384 B

  hipLaunchKernelGGL(k0_prep, dim3(608), dim3(256), 0, stream,
                     fw1, fw2, fw3, fw1s, fw2s, fw3s);
  hipLaunchKernelGGL(k1_wc, dim3(128), dim3(256), 0, stream, psi, dw, wc);
  hipLaunchKernelGGL(k2_disco_head, dim3(8, 128, 2), dim3(256), 0, stream,
                     x, wc, db, hw1, hb1, hw2, hb2, outb);
  hipLaunchKernelGGL(k3_mfma, dim3(2048), dim3(256), 0, stream,
                     fw1s, fw2s, fw3s, fb1, fb2, fb3, outb);
}

// Round 3
// 254.740 us; speedup vs baseline: 3.8453x; 2.2750x over previous
//
#include <hip/hip_runtime.h>
#include <math.h>

// Problem constants
// B=2, H=128, W=256, MD=34, LD=32, NH=4, HD=8, SH=64, K=25, P=7, R=3,
// FF1=512, FF2=256

typedef __attribute__((ext_vector_type(8))) short bfrag;    // 8 bf16 = 4 VGPR
typedef __attribute__((ext_vector_type(4))) float ffrag;    // 4 f32 acc
typedef __attribute__((ext_vector_type(4))) short short4v;  // 8B

__device__ __forceinline__ float gelu_f(float v) {
    return 0.5f * v * (1.0f + erff(v * 0.70710678118654752440f));
}

__device__ __forceinline__ short f2bf(float f) {
  union { float f; unsigned u; } v; v.f = f;
  unsigned r = (v.u + 0x7fffu + ((v.u >> 16) & 1u)) >> 16;  // RNE
  return (short)r;
}

// ---------------------------------------------------------------------------
// K0: swizzle fw1/fw2/fw3 (for k3) and hw1 (for k2) into bf16 B-fragments.
// B-frag (16x16x32): lane holds B[k][n], n=lane&15, k=(lane>>4)*8+j.
// ---------------------------------------------------------------------------
__global__ __launch_bounds__(256) void k0_prep(
    const float* __restrict__ fw1, const float* __restrict__ fw2,
    const float* __restrict__ fw3, const float* __restrict__ hw1,
    short* __restrict__ fw1s, short* __restrict__ fw2s,
    short* __restrict__ fw3s, short* __restrict__ hw1b) {
  const int e = blockIdx.x * 256 + threadIdx.x;
  if (e < 16384) {                       // fw1: K=32 (1 kt), N=512 (32 nt)
    const int j = e & 7, lane = (e >> 3) & 63, nt = e >> 9;
    const int k = (lane >> 4) * 8 + j, n = nt * 16 + (lane & 15);
    fw1s[e] = f2bf(fw1[k * 512 + n]);
  } else if (e < 16384 + 131072) {       // fw2: K=512 (16 kt), N=256 (16 nt)
    const int e2 = e - 16384;
    const int j = e2 & 7, lane = (e2 >> 3) & 63;
    const int nt = (e2 >> 9) & 15, kt = e2 >> 13;
    const int k = kt * 32 + (lane >> 4) * 8 + j, n = nt * 16 + (lane & 15);
    fw2s[e2] = f2bf(fw2[k * 256 + n]);
  } else if (e < 16384 + 131072 + 8192) { // fw3: K=256 (8 kt), N=32 (2 nt)
    const int e3 = e - 147456;
    const int j = e3 & 7, lane = (e3 >> 3) & 63;
    const int nt = (e3 >> 9) & 1, kt = e3 >> 10;
    const int k = kt * 32 + (lane >> 4) * 8 + j, n = nt * 16 + (lane & 15);
    fw3s[e3] = f2bf(fw3[k * 32 + n]);
  } else if (e < 163840) {               // hw1: per head, K=64 (2kt), N=32 (2nt)
    const int e4 = e - 155648;
    const int jj = e4 & 7, lane = (e4 >> 3) & 63;
    const int fr = (e4 >> 9) & 3, n = e4 >> 11;    // fr = kt*2+nt
    const int kt = fr >> 1, nt = fr & 1;
    const int k = kt * 32 + (lane >> 4) * 8 + jj;
    const int o = nt * 16 + (lane & 15);
    hw1b[e4] = f2bf(hw1[n * 2048 + k * 32 + o]);
  }
}

// ---------------------------------------------------------------------------
// K1: conv weights as bf16 B-fragments per latitude.
// wcb[h][(kt*4+nt)*512 + lane*8 + jj]: k=kt*32+(lane>>4)*8+jj -> (r=k>>3,j=k&7),
// f=nt*16+(lane&15); value = sum_kk dw[f,kk]*psi[kk,h,r*7+j], 0 if r==7||j==7.
// ---------------------------------------------------------------------------
__global__ __launch_bounds__(256) void k1_wcb(
    const float* __restrict__ psi, const float* __restrict__ dw,
    short* __restrict__ wcb) {
  __shared__ float psiL[25 * 49];
  const int h = blockIdx.x;
  for (int e = threadIdx.x; e < 1225; e += 256)
    psiL[e] = psi[(e / 49) * (128 * 49) + h * 49 + (e % 49)];
  __syncthreads();
  short* outp = wcb + h * 4096;
  for (int idx = threadIdx.x; idx < 4096; idx += 256) {
    const int jj = idx & 7, lane = (idx >> 3) & 63;
    const int fnt = (idx >> 9) & 3, kt = idx >> 11;
    const int k = kt * 32 + (lane >> 4) * 8 + jj;
    const int f = fnt * 16 + (lane & 15);
    const int r = k >> 3, j = k & 7;
    float acc = 0.f;
    if (r < 7 && j < 7) {
      const int p = r * 7 + j;
#pragma unroll
      for (int kk = 0; kk < 25; ++kk)
        acc += dw[f * 25 + kk] * psiL[kk * 49 + p];
    }
    outp[idx] = f2bf(acc);
  }
}

// ---------------------------------------------------------------------------
// K2: DISCO conv + head MLP via MFMA. grid (8,128,2), block 256 (4 waves).
// M = c*32+w (1024 rows/block): mt = c*2+(w>>4), m = w&15 -> wave==head.
// Conv: A = taps (K=64: k=r*8+j, r/j=7 padded 0), B = wcb[h].
// MLP1: d-tile LDS roundtrip (C-layout -> A-layout), B = hw1b[head].
// MLP2: gelu + hw2 dot via shfl_xor butterfly; residual exact from x.
// ---------------------------------------------------------------------------
__global__ __launch_bounds__(256, 3) void k2_disco_mfma(
    const float* __restrict__ x,   const short* __restrict__ wcb,
    const float* __restrict__ db,  const short* __restrict__ hw1b,
    const float* __restrict__ hb1, const float* __restrict__ hw2,
    const float* __restrict__ hb2, float* __restrict__ outb) {
  // sX: [c][r 0..7][wp 0..47], c-stride 386 (193 dw == 1 mod 32: stage writes
  // conflict-free; r-stride 24 dw: quad offsets 0,24,16,8 -> frag reads free).
  __shared__ __align__(16) short sX[32 * 386];          // 24704 B
  // per-wave d tile [m 16][f pad 76]: b16 write quads 0,24,16,8 dw apart; 8B-
  // aligned short4 reads for MLP1 A-frags.
  __shared__ __align__(16) short sD[4][16 * 76];        //  9728 B

  const int tid = threadIdx.x;
  const int w0  = blockIdx.x * 32;
  const int h   = blockIdx.y;
  const int b   = blockIdx.z;

  // zero sX: pad regions (r=7 row, wp=38..47) must be 0.0bf16, never NaN
  {
    int4* p = (int4*)sX;
    int4 z; z.x = z.y = z.z = z.w = 0;
    for (int e = tid; e < (32 * 386) / 8; e += 256) p[e] = z;
  }
  __syncthreads();

  // stage x tile as bf16: wp=0..38 (covers taps j=0..7 for w=0..31), r=0..6
  for (int e = tid; e < 7 * 39 * 32; e += 256) {
    const int c = e & 31, t = e >> 5;
    const int wp = t % 39, r = t / 39;
    int hr = h - 3 + r; hr = hr < 0 ? 0 : (hr > 127 ? 127 : hr);
    const int wr = (w0 - 3 + wp) & 255;
    sX[c * 386 + r * 48 + wp] = f2bf(x[((b * 128 + hr) * 256 + wr) * 34 + c]);
  }
  __syncthreads();

  const int lane = tid & 63, lm = lane & 15, lq = lane >> 4;
  const int n = tid >> 6;  // wave == head (wave-uniform)

  float dbv[4];
#pragma unroll
  for (int nt = 0; nt < 4; ++nt) dbv[nt] = db[nt * 16 + lm];
  float hb1v[2], hw2v[2];
#pragma unroll
  for (int nt = 0; nt < 2; ++nt) {
    hb1v[nt] = hb1[n * 32 + nt * 16 + lm];
    hw2v[nt] = hw2[n * 32 + nt * 16 + lm];
  }
  const float hb2n = hb2[n];

  // conv B-frags (block-uniform per h): [kt][nt]
  bfrag cB[2][4];
#pragma unroll
  for (int kt = 0; kt < 2; ++kt)
#pragma unroll
    for (int nt = 0; nt < 4; ++nt)
      cB[kt][nt] = *(const bfrag*)(wcb + h * 4096 + (kt * 4 + nt) * 512 + lane * 8);
  // MLP1 B-frags (wave-uniform per head): [kt][nt]
  bfrag mB[2][2];
#pragma unroll
  for (int kt = 0; kt < 2; ++kt)
#pragma unroll
    for (int nt = 0; nt < 2; ++nt)
      mB[kt][nt] = *(const bfrag*)(hw1b + n * 2048 + (kt * 2 + nt) * 512 + lane * 8);

  short* sDw = (short*)sD[n];

#pragma unroll 1
  for (int i = 0; i < 16; ++i) {
    const int mt = n * 16 + i;
    const int c  = mt >> 1;
    const int wh = (mt & 1) * 16;

    // conv A-frags: lane holds taps A[m=lm][k=lq*8+jj], k=r*8+j
    const short* sxb = sX + c * 386 + wh + lm;
    bfrag aF0, aF1;
#pragma unroll
    for (int jj = 0; jj < 8; ++jj) aF0[jj] = sxb[lq * 48 + jj];
#pragma unroll
    for (int jj = 0; jj < 8; ++jj) aF1[jj] = sxb[(4 + lq) * 48 + jj];

    ffrag dacc[4];
#pragma unroll
    for (int nt = 0; nt < 4; ++nt) dacc[nt] = ffrag{0.f, 0.f, 0.f, 0.f};
#pragma unroll
    for (int nt = 0; nt < 4; ++nt) {
      dacc[nt] = __builtin_amdgcn_mfma_f32_16x16x32_bf16(aF0, cB[0][nt], dacc[nt], 0, 0, 0);
      dacc[nt] = __builtin_amdgcn_mfma_f32_16x16x32_bf16(aF1, cB[1][nt], dacc[nt], 0, 0, 0);
    }

    // d (C-layout: col f=nt*16+lm, row lq*4+r) + bias -> per-wave LDS tile
#pragma unroll
    for (int nt = 0; nt < 4; ++nt)
#pragma unroll
      for (int r = 0; r < 4; ++r)
        sDw[(lq * 4 + r) * 76 + nt * 16 + lm] = f2bf(dacc[nt][r] + dbv[nt]);
    // same-wave DS ops are processed in order -> no barrier needed

    // MLP1 A-frags: A[m=lm][k=lq*8+jj] from d-tile (contiguous, 8B aligned)
    bfrag a1[2];
#pragma unroll
    for (int kt = 0; kt < 2; ++kt) {
      const short* ap = sDw + lm * 76 + kt * 32 + lq * 8;
      const short4v lo = *(const short4v*)(ap);
      const short4v hi = *(const short4v*)(ap + 4);
      bfrag t;
      t[0] = lo[0]; t[1] = lo[1]; t[2] = lo[2]; t[3] = lo[3];
      t[4] = hi[0]; t[5] = hi[1]; t[6] = hi[2]; t[7] = hi[3];
      a1[kt] = t;
    }

    ffrag h1[2];
    h1[0] = ffrag{0.f, 0.f, 0.f, 0.f};
    h1[1] = ffrag{0.f, 0.f, 0.f, 0.f};
#pragma unroll
    for (int nt = 0; nt < 2; ++nt) {
      h1[nt] = __builtin_amdgcn_mfma_f32_16x16x32_bf16(a1[0], mB[0][nt], h1[nt], 0, 0, 0);
      h1[nt] = __builtin_amdgcn_mfma_f32_16x16x32_bf16(a1[1], mB[1][nt], h1[nt], 0, 0, 0);
    }

    // MLP2: out[row] = sum_o gelu(h1[row][o])*hw2[o]; reduce over 16 lanes
    float vsum[4];
#pragma unroll
    for (int r = 0; r < 4; ++r)
      vsum[r] = gelu_f(h1[0][r] + hb1v[0]) * hw2v[0] +
                gelu_f(h1[1][r] + hb1v[1]) * hw2v[1];
#pragma unroll
    for (int m = 1; m < 16; m <<= 1)
#pragma unroll
      for (int r = 0; r < 4; ++r)
        vsum[r] += __shfl_xor(vsum[r], m, 64);

    if (lm == 0) {
#pragma unroll
      for (int r = 0; r < 4; ++r) {
        const int gw = w0 + wh + lq * 4 + r;
        const int idx = ((b * 128 + h) * 256 + gw) * 34 + c;
        outb[idx] = vsum[r] + hb2n + x[idx];   // residual exact fp32
      }
    }
  }

  // sincos passthrough
  if (tid < 64) {
    const int wl = tid >> 1;
    const int sc = tid & 1;
    const int idx = ((b * 128 + h) * 256 + (w0 + wl)) * 34 + 32 + sc;
    outb[idx] = x[idx];
  }
}

// ---------------------------------------------------------------------------
// K3: fused MLP 32 -> 512(gelu) -> 256(gelu) -> 32 (+residual), bf16 MFMA.
// (unchanged from R1)
// ---------------------------------------------------------------------------
__global__ __launch_bounds__(256, 3) void k3_mfma(
    const short* __restrict__ fw1s, const short* __restrict__ fw2s,
    const short* __restrict__ fw3s,
    const float* __restrict__ fb1, const float* __restrict__ fb2,
    const float* __restrict__ fb3, float* __restrict__ outb) {
  __shared__ short sT1[32 * 520];   // 33280 B
  __shared__ short sT2[32 * 264];   // 16896 B

  const int tid  = threadIdx.x;
  const int lane = tid & 63;
  const int wave = tid >> 6;
  const int pix0 = blockIdx.x * 32;
  const int lm   = lane & 15;
  const int lq   = lane >> 4;
  const int koff = lq * 8;

  bfrag aF[2];
#pragma unroll
  for (int mt = 0; mt < 2; ++mt) {
    const float* ap = outb + (pix0 + mt * 16 + lm) * 34 + koff;
    float2 v0 = *(const float2*)(ap + 0);
    float2 v1 = *(const float2*)(ap + 2);
    float2 v2 = *(const float2*)(ap + 4);
    float2 v3 = *(const float2*)(ap + 6);
    bfrag a;
    a[0] = f2bf(v0.x); a[1] = f2bf(v0.y); a[2] = f2bf(v1.x); a[3] = f2bf(v1.y);
    a[4] = f2bf(v2.x); a[5] = f2bf(v2.y); a[6] = f2bf(v3.x); a[7] = f2bf(v3.y);
    aF[mt] = a;
  }

#pragma unroll
  for (int ni = 0; ni < 8; ++ni) {
    const int nt = wave * 8 + ni;
    const bfrag bv = *(const bfrag*)(fw1s + nt * 512 + lane * 8);
#pragma unroll
    for (int mt = 0; mt < 2; ++mt) {
      ffrag c = {0.f, 0.f, 0.f, 0.f};
      c = __builtin_amdgcn_mfma_f32_16x16x32_bf16(aF[mt], bv, c, 0, 0, 0);
      const int col = nt * 16 + lm;
      const float bias = fb1[col];
#pragma unroll
      for (int r = 0; r < 4; ++r) {
        const int row = mt * 16 + lq * 4 + r;
        sT1[row * 520 + col] = f2bf(gelu_f(c[r] + bias));
      }
    }
  }
  __syncthreads();

  const int n0 = wave * 4;
  ffrag acc[2][4];
#pragma unroll
  for (int mt = 0; mt < 2; ++mt)
#pragma unroll
    for (int ni = 0; ni < 4; ++ni) acc[mt][ni] = ffrag{0.f, 0.f, 0.f, 0.f};

  const short* sA0 = &sT1[lm * 520 + koff];
  const short* sA1 = sA0 + 16 * 520;
  const short* w2p = fw2s + n0 * 512 + lane * 8;
#pragma unroll 4
  for (int kt = 0; kt < 16; ++kt) {
    const bfrag a0 = *(const bfrag*)(sA0 + kt * 32);
    const bfrag a1 = *(const bfrag*)(sA1 + kt * 32);
    bfrag bv[4];
#pragma unroll
    for (int ni = 0; ni < 4; ++ni)
      bv[ni] = *(const bfrag*)(w2p + kt * 8192 + ni * 512);
#pragma unroll
    for (int ni = 0; ni < 4; ++ni) {
      acc[0][ni] = __builtin_amdgcn_mfma_f32_16x16x32_bf16(a0, bv[ni], acc[0][ni], 0, 0, 0);
      acc[1][ni] = __builtin_amdgcn_mfma_f32_16x16x32_bf16(a1, bv[ni], acc[1][ni], 0, 0, 0);
    }
  }
#pragma unroll
  for (int mt = 0; mt < 2; ++mt)
#pragma unroll
    for (int ni = 0; ni < 4; ++ni) {
      const int col = (n0 + ni) * 16 + lm;
      const float bias = fb2[col];
#pragma unroll
      for (int r = 0; r < 4; ++r) {
        const int row = mt * 16 + lq * 4 + r;
        sT2[row * 264 + col] = f2bf(gelu_f(acc[mt][ni][r] + bias));
      }
    }
  __syncthreads();

  const int mt3 = wave & 1;
  const int nt3 = wave >> 1;
  ffrag c3 = {0.f, 0.f, 0.f, 0.f};
  const short* sA3 = &sT2[(mt3 * 16 + lm) * 264 + koff];
  const short* w3p = fw3s + nt3 * 512 + lane * 8;
#pragma unroll
  for (int kt = 0; kt < 8; ++kt) {
    const bfrag a = *(const bfrag*)(sA3 + kt * 32);
    const bfrag bv = *(const bfrag*)(w3p + kt * 1024);
    c3 = __builtin_amdgcn_mfma_f32_16x16x32_bf16(a, bv, c3, 0, 0, 0);
  }
  {
    const int col = nt3 * 16 + lm;
    const float bias = fb3[col];
#pragma unroll
    for (int r = 0; r < 4; ++r) {
      const int row = mt3 * 16 + lq * 4 + r;
      const int p = pix0 + row;
      const float res = outb[p * 34 + col];
      outb[p * 34 + col] = c3[r] + bias + res;
    }
  }
}

// ---------------------------------------------------------------------------
extern "C" void kernel_launch(void* const* d_in, const int* in_sizes, int n_in,
                              void* d_out, int out_size, void* d_ws, size_t ws_size,
                              hipStream_t stream) {
  const float* x   = (const float*)d_in[0];
  const float* psi = (const float*)d_in[1];
  const float* dw  = (const float*)d_in[2];
  const float* db  = (const float*)d_in[3];
  const float* hw1 = (const float*)d_in[4];
  const float* hb1 = (const float*)d_in[5];
  const float* hw2 = (const float*)d_in[6];
  const float* hb2 = (const float*)d_in[7];
  const float* fw1 = (const float*)d_in[8];
  const float* fb1 = (const float*)d_in[9];
  const float* fw2 = (const float*)d_in[10];
  const float* fb2 = (const float*)d_in[11];
  const float* fw3 = (const float*)d_in[12];
  const float* fb3 = (const float*)d_in[13];
  float* outb = (float*)d_out;

  // workspace (all 16B-aligned): total 1376256 B
  short* wcb  = (short*)d_ws;        // 128*4096 = 524288 shorts
  short* fw1s = wcb + 524288;        // 16384
  short* fw2s = fw1s + 16384;        // 131072
  short* fw3s = fw2s + 131072;       // 8192
  short* hw1b = fw3s + 8192;         // 8192

  hipLaunchKernelGGL(k0_prep, dim3(640), dim3(256), 0, stream,
                     fw1, fw2, fw3, hw1, fw1s, fw2s, fw3s, hw1b);
  hipLaunchKernelGGL(k1_wcb, dim3(128), dim3(256), 0, stream, psi, dw, wcb);
  hipLaunchKernelGGL(k2_disco_mfma, dim3(8, 128, 2), dim3(256), 0, stream,
                     x, wcb, db, hw1b, hb1, hw2, hb2, outb);
  hipLaunchKernelGGL(k3_mfma, dim3(2048), dim3(256), 0, stream,
                     fw1s, fw2s, fw3s, fb1, fb2, fb3, outb);
}

// Round 4
// 221.095 us; speedup vs baseline: 4.4305x; 1.1522x over previous
//
#include <hip/hip_runtime.h>
#include <math.h>

// Problem constants
// B=2, H=128, W=256, MD=34, LD=32, NH=4, HD=8, SH=64, K=25, P=7, R=3,
// FF1=512, FF2=256

typedef __attribute__((ext_vector_type(8))) short bfrag;    // 8 bf16 = 4 VGPR
typedef __attribute__((ext_vector_type(4))) float ffrag;    // 4 f32 acc
typedef __attribute__((ext_vector_type(4))) short short4v;  // 8B

// Fast tanh-form GELU: v * sigmoid(2*sqrt(2/pi)*(v + 0.044715 v^3)).
// Max |diff| vs exact erf-GELU ~3e-3, well under the bf16 threshold slack.
// ~8 VALU ops (vs ~30 for ocml erff).
__device__ __forceinline__ float gelu_f(float v) {
  const float z = v * (1.5957691216f + 0.0713548163f * v * v);
  const float e = __expf(-z);                       // v_exp_f32 path
  return v * __builtin_amdgcn_rcpf(1.0f + e);       // v_rcp_f32
}

// exact RNE (cold paths: weight prep)
__device__ __forceinline__ short f2bf(float f) {
  union { float f; unsigned u; } v; v.f = f;
  unsigned r = (v.u + 0x7fffu + ((v.u >> 16) & 1u)) >> 16;
  return (short)r;
}

// round-half-up (2 VALU ops); differs from RNE only on exact ties (1 ulp)
__device__ __forceinline__ short f2bf_fast(float f) {
  union { float f; unsigned u; } v; v.f = f;
  return (short)((v.u + 0x8000u) >> 16);
}

// ---------------------------------------------------------------------------
// K0: swizzle fw1/fw2/fw3 (for k3) and hw1 (for k2) into bf16 B-fragments.
// B-frag (16x16x32): lane holds B[k][n], n=lane&15, k=(lane>>4)*8+j.
// ---------------------------------------------------------------------------
__global__ __launch_bounds__(256) void k0_prep(
    const float* __restrict__ fw1, const float* __restrict__ fw2,
    const float* __restrict__ fw3, const float* __restrict__ hw1,
    short* __restrict__ fw1s, short* __restrict__ fw2s,
    short* __restrict__ fw3s, short* __restrict__ hw1b) {
  const int e = blockIdx.x * 256 + threadIdx.x;
  if (e < 16384) {                       // fw1: K=32 (1 kt), N=512 (32 nt)
    const int j = e & 7, lane = (e >> 3) & 63, nt = e >> 9;
    const int k = (lane >> 4) * 8 + j, n = nt * 16 + (lane & 15);
    fw1s[e] = f2bf(fw1[k * 512 + n]);
  } else if (e < 16384 + 131072) {       // fw2: K=512 (16 kt), N=256 (16 nt)
    const int e2 = e - 16384;
    const int j = e2 & 7, lane = (e2 >> 3) & 63;
    const int nt = (e2 >> 9) & 15, kt = e2 >> 13;
    const int k = kt * 32 + (lane >> 4) * 8 + j, n = nt * 16 + (lane & 15);
    fw2s[e2] = f2bf(fw2[k * 256 + n]);
  } else if (e < 16384 + 131072 + 8192) { // fw3: K=256 (8 kt), N=32 (2 nt)
    const int e3 = e - 147456;
    const int j = e3 & 7, lane = (e3 >> 3) & 63;
    const int nt = (e3 >> 9) & 1, kt = e3 >> 10;
    const int k = kt * 32 + (lane >> 4) * 8 + j, n = nt * 16 + (lane & 15);
    fw3s[e3] = f2bf(fw3[k * 32 + n]);
  } else if (e < 163840) {               // hw1: per head, K=64 (2kt), N=32 (2nt)
    const int e4 = e - 155648;
    const int jj = e4 & 7, lane = (e4 >> 3) & 63;
    const int fr = (e4 >> 9) & 3, n = e4 >> 11;    // fr = kt*2+nt
    const int kt = fr >> 1, nt = fr & 1;
    const int k = kt * 32 + (lane >> 4) * 8 + jj;
    const int o = nt * 16 + (lane & 15);
    hw1b[e4] = f2bf(hw1[n * 2048 + k * 32 + o]);
  }
}

// ---------------------------------------------------------------------------
// K1: conv weights as bf16 B-fragments per latitude.
// ---------------------------------------------------------------------------
__global__ __launch_bounds__(256) void k1_wcb(
    const float* __restrict__ psi, const float* __restrict__ dw,
    short* __restrict__ wcb) {
  __shared__ float psiL[25 * 49];
  const int h = blockIdx.x;
  for (int e = threadIdx.x; e < 1225; e += 256)
    psiL[e] = psi[(e / 49) * (128 * 49) + h * 49 + (e % 49)];
  __syncthreads();
  short* outp = wcb + h * 4096;
  for (int idx = threadIdx.x; idx < 4096; idx += 256) {
    const int jj = idx & 7, lane = (idx >> 3) & 63;
    const int fnt = (idx >> 9) & 3, kt = idx >> 11;
    const int k = kt * 32 + (lane >> 4) * 8 + jj;
    const int f = fnt * 16 + (lane & 15);
    const int r = k >> 3, j = k & 7;
    float acc = 0.f;
    if (r < 7 && j < 7) {
      const int p = r * 7 + j;
#pragma unroll
      for (int kk = 0; kk < 25; ++kk)
        acc += dw[f * 25 + kk] * psiL[kk * 49 + p];
    }
    outp[idx] = f2bf(acc);
  }
}

// ---------------------------------------------------------------------------
// K2: DISCO conv + head MLP via MFMA. grid (8,128,2), block 256 (4 waves).
// ---------------------------------------------------------------------------
__global__ __launch_bounds__(256, 3) void k2_disco_mfma(
    const float* __restrict__ x,   const short* __restrict__ wcb,
    const float* __restrict__ db,  const short* __restrict__ hw1b,
    const float* __restrict__ hb1, const float* __restrict__ hw2,
    const float* __restrict__ hb2, float* __restrict__ outb) {
  __shared__ __align__(16) short sX[32 * 386];          // 24704 B
  __shared__ __align__(16) short sD[4][16 * 76];        //  9728 B

  const int tid = threadIdx.x;
  const int w0  = blockIdx.x * 32;
  const int h   = blockIdx.y;
  const int b   = blockIdx.z;

  // zero sX: pad regions (r=7 row, wp=38..47) must be 0.0bf16, never NaN
  {
    int4* p = (int4*)sX;
    int4 z; z.x = z.y = z.z = z.w = 0;
    for (int e = tid; e < (32 * 386) / 8; e += 256) p[e] = z;
  }
  __syncthreads();

  // stage x tile as bf16 (float2 over c-pairs: coalesced 8B, 2 ops/cvt)
  for (int e = tid; e < 7 * 39 * 16; e += 256) {
    const int c2 = e & 15, t = e >> 4;
    const int wp = t % 39, r = t / 39;
    int hr = h - 3 + r; hr = hr < 0 ? 0 : (hr > 127 ? 127 : hr);
    const int wr = (w0 - 3 + wp) & 255;
    const float2 v = *(const float2*)&x[((b * 128 + hr) * 256 + wr) * 34 + c2 * 2];
    short* dp = &sX[(c2 * 2) * 386 + r * 48 + wp];
    dp[0]   = f2bf_fast(v.x);
    dp[386] = f2bf_fast(v.y);
  }
  __syncthreads();

  const int lane = tid & 63, lm = lane & 15, lq = lane >> 4;
  const int n = tid >> 6;  // wave == head (wave-uniform)

  float dbv[4];
#pragma unroll
  for (int nt = 0; nt < 4; ++nt) dbv[nt] = db[nt * 16 + lm];
  float hb1v[2], hw2v[2];
#pragma unroll
  for (int nt = 0; nt < 2; ++nt) {
    hb1v[nt] = hb1[n * 32 + nt * 16 + lm];
    hw2v[nt] = hw2[n * 32 + nt * 16 + lm];
  }
  const float hb2n = hb2[n];

  bfrag cB[2][4];
#pragma unroll
  for (int kt = 0; kt < 2; ++kt)
#pragma unroll
    for (int nt = 0; nt < 4; ++nt)
      cB[kt][nt] = *(const bfrag*)(wcb + h * 4096 + (kt * 4 + nt) * 512 + lane * 8);
  bfrag mB[2][2];
#pragma unroll
  for (int kt = 0; kt < 2; ++kt)
#pragma unroll
    for (int nt = 0; nt < 2; ++nt)
      mB[kt][nt] = *(const bfrag*)(hw1b + n * 2048 + (kt * 2 + nt) * 512 + lane * 8);

  short* sDw = (short*)sD[n];

#pragma unroll 1
  for (int i = 0; i < 16; ++i) {
    const int mt = n * 16 + i;
    const int c  = mt >> 1;
    const int wh = (mt & 1) * 16;

    const short* sxb = sX + c * 386 + wh + lm;
    bfrag aF0, aF1;
#pragma unroll
    for (int jj = 0; jj < 8; ++jj) aF0[jj] = sxb[lq * 48 + jj];
#pragma unroll
    for (int jj = 0; jj < 8; ++jj) aF1[jj] = sxb[(4 + lq) * 48 + jj];

    ffrag dacc[4];
#pragma unroll
    for (int nt = 0; nt < 4; ++nt) dacc[nt] = ffrag{0.f, 0.f, 0.f, 0.f};
#pragma unroll
    for (int nt = 0; nt < 4; ++nt) {
      dacc[nt] = __builtin_amdgcn_mfma_f32_16x16x32_bf16(aF0, cB[0][nt], dacc[nt], 0, 0, 0);
      dacc[nt] = __builtin_amdgcn_mfma_f32_16x16x32_bf16(aF1, cB[1][nt], dacc[nt], 0, 0, 0);
    }

#pragma unroll
    for (int nt = 0; nt < 4; ++nt)
#pragma unroll
      for (int r = 0; r < 4; ++r)
        sDw[(lq * 4 + r) * 76 + nt * 16 + lm] = f2bf_fast(dacc[nt][r] + dbv[nt]);
    // same-wave DS ops in order -> no barrier

    bfrag a1[2];
#pragma unroll
    for (int kt = 0; kt < 2; ++kt) {
      const short* ap = sDw + lm * 76 + kt * 32 + lq * 8;
      const short4v lo = *(const short4v*)(ap);
      const short4v hi = *(const short4v*)(ap + 4);
      bfrag t;
      t[0] = lo[0]; t[1] = lo[1]; t[2] = lo[2]; t[3] = lo[3];
      t[4] = hi[0]; t[5] = hi[1]; t[6] = hi[2]; t[7] = hi[3];
      a1[kt] = t;
    }

    ffrag h1[2];
    h1[0] = ffrag{0.f, 0.f, 0.f, 0.f};
    h1[1] = ffrag{0.f, 0.f, 0.f, 0.f};
#pragma unroll
    for (int nt = 0; nt < 2; ++nt) {
      h1[nt] = __builtin_amdgcn_mfma_f32_16x16x32_bf16(a1[0], mB[0][nt], h1[nt], 0, 0, 0);
      h1[nt] = __builtin_amdgcn_mfma_f32_16x16x32_bf16(a1[1], mB[1][nt], h1[nt], 0, 0, 0);
    }

    float vsum[4];
#pragma unroll
    for (int r = 0; r < 4; ++r)
      vsum[r] = gelu_f(h1[0][r] + hb1v[0]) * hw2v[0] +
                gelu_f(h1[1][r] + hb1v[1]) * hw2v[1];
#pragma unroll
    for (int m = 1; m < 16; m <<= 1)
#pragma unroll
      for (int r = 0; r < 4; ++r)
        vsum[r] += __shfl_xor(vsum[r], m, 64);

    if (lm == 0) {
#pragma unroll
      for (int r = 0; r < 4; ++r) {
        const int gw = w0 + wh + lq * 4 + r;
        const int idx = ((b * 128 + h) * 256 + gw) * 34 + c;
        outb[idx] = vsum[r] + hb2n + x[idx];   // residual exact fp32
      }
    }
  }

  // sincos passthrough
  if (tid < 64) {
    const int wl = tid >> 1;
    const int sc = tid & 1;
    const int idx = ((b * 128 + h) * 256 + (w0 + wl)) * 34 + 32 + sc;
    outb[idx] = x[idx];
  }
}

// ---------------------------------------------------------------------------
// K3: fused MLP 32 -> 512(gelu) -> 256(gelu) -> 32 (+residual), bf16 MFMA.
// ---------------------------------------------------------------------------
__global__ __launch_bounds__(256, 3) void k3_mfma(
    const short* __restrict__ fw1s, const short* __restrict__ fw2s,
    const short* __restrict__ fw3s,
    const float* __restrict__ fb1, const float* __restrict__ fb2,
    const float* __restrict__ fb3, float* __restrict__ outb) {
  __shared__ short sT1[32 * 520];   // 33280 B
  __shared__ short sT2[32 * 264];   // 16896 B

  const int tid  = threadIdx.x;
  const int lane = tid & 63;
  const int wave = tid >> 6;
  const int pix0 = blockIdx.x * 32;
  const int lm   = lane & 15;
  const int lq   = lane >> 4;
  const int koff = lq * 8;

  bfrag aF[2];
#pragma unroll
  for (int mt = 0; mt < 2; ++mt) {
    const float* ap = outb + (pix0 + mt * 16 + lm) * 34 + koff;
    float2 v0 = *(const float2*)(ap + 0);
    float2 v1 = *(const float2*)(ap + 2);
    float2 v2 = *(const float2*)(ap + 4);
    float2 v3 = *(const float2*)(ap + 6);
    bfrag a;
    a[0] = f2bf_fast(v0.x); a[1] = f2bf_fast(v0.y);
    a[2] = f2bf_fast(v1.x); a[3] = f2bf_fast(v1.y);
    a[4] = f2bf_fast(v2.x); a[5] = f2bf_fast(v2.y);
    a[6] = f2bf_fast(v3.x); a[7] = f2bf_fast(v3.y);
    aF[mt] = a;
  }

#pragma unroll
  for (int ni = 0; ni < 8; ++ni) {
    const int nt = wave * 8 + ni;
    const bfrag bv = *(const bfrag*)(fw1s + nt * 512 + lane * 8);
#pragma unroll
    for (int mt = 0; mt < 2; ++mt) {
      ffrag c = {0.f, 0.f, 0.f, 0.f};
      c = __builtin_amdgcn_mfma_f32_16x16x32_bf16(aF[mt], bv, c, 0, 0, 0);
      const int col = nt * 16 + lm;
      const float bias = fb1[col];
#pragma unroll
      for (int r = 0; r < 4; ++r) {
        const int row = mt * 16 + lq * 4 + r;
        sT1[row * 520 + col] = f2bf_fast(gelu_f(c[r] + bias));
      }
    }
  }
  __syncthreads();

  const int n0 = wave * 4;
  ffrag acc[2][4];
#pragma unroll
  for (int mt = 0; mt < 2; ++mt)
#pragma unroll
    for (int ni = 0; ni < 4; ++ni) acc[mt][ni] = ffrag{0.f, 0.f, 0.f, 0.f};

  const short* sA0 = &sT1[lm * 520 + koff];
  const short* sA1 = sA0 + 16 * 520;
  const short* w2p = fw2s + n0 * 512 + lane * 8;
#pragma unroll 4
  for (int kt = 0; kt < 16; ++kt) {
    const bfrag a0 = *(const bfrag*)(sA0 + kt * 32);
    const bfrag a1 = *(const bfrag*)(sA1 + kt * 32);
    bfrag bv[4];
#pragma unroll
    for (int ni = 0; ni < 4; ++ni)
      bv[ni] = *(const bfrag*)(w2p + kt * 8192 + ni * 512);
#pragma unroll
    for (int ni = 0; ni < 4; ++ni) {
      acc[0][ni] = __builtin_amdgcn_mfma_f32_16x16x32_bf16(a0, bv[ni], acc[0][ni], 0, 0, 0);
      acc[1][ni] = __builtin_amdgcn_mfma_f32_16x16x32_bf16(a1, bv[ni], acc[1][ni], 0, 0, 0);
    }
  }
#pragma unroll
  for (int mt = 0; mt < 2; ++mt)
#pragma unroll
    for (int ni = 0; ni < 4; ++ni) {
      const int col = (n0 + ni) * 16 + lm;
      const float bias = fb2[col];
#pragma unroll
      for (int r = 0; r < 4; ++r) {
        const int row = mt * 16 + lq * 4 + r;
        sT2[row * 264 + col] = f2bf_fast(gelu_f(acc[mt][ni][r] + bias));
      }
    }
  __syncthreads();

  const int mt3 = wave & 1;
  const int nt3 = wave >> 1;
  ffrag c3 = {0.f, 0.f, 0.f, 0.f};
  const short* sA3 = &sT2[(mt3 * 16 + lm) * 264 + koff];
  const short* w3p = fw3s + nt3 * 512 + lane * 8;
#pragma unroll
  for (int kt = 0; kt < 8; ++kt) {
    const bfrag a = *(const bfrag*)(sA3 + kt * 32);
    const bfrag bv = *(const bfrag*)(w3p + kt * 1024);
    c3 = __builtin_amdgcn_mfma_f32_16x16x32_bf16(a, bv, c3, 0, 0, 0);
  }
  {
    const int col = nt3 * 16 + lm;
    const float bias = fb3[col];
#pragma unroll
    for (int r = 0; r < 4; ++r) {
      const int row = mt3 * 16 + lq * 4 + r;
      const int p = pix0 + row;
      const float res = outb[p * 34 + col];
      outb[p * 34 + col] = c3[r] + bias + res;
    }
  }
}

// ---------------------------------------------------------------------------
extern "C" void kernel_launch(void* const* d_in, const int* in_sizes, int n_in,
                              void* d_out, int out_size, void* d_ws, size_t ws_size,
                              hipStream_t stream) {
  const float* x   = (const float*)d_in[0];
  const float* psi = (const float*)d_in[1];
  const float* dw  = (const float*)d_in[2];
  const float* db  = (const float*)d_in[3];
  const float* hw1 = (const float*)d_in[4];
  const float* hb1 = (const float*)d_in[5];
  const float* hw2 = (const float*)d_in[6];
  const float* hb2 = (const float*)d_in[7];
  const float* fw1 = (const float*)d_in[8];
  const float* fb1 = (const float*)d_in[9];
  const float* fw2 = (const float*)d_in[10];
  const float* fb2 = (const float*)d_in[11];
  const float* fw3 = (const float*)d_in[12];
  const float* fb3 = (const float*)d_in[13];
  float* outb = (float*)d_out;

  short* wcb  = (short*)d_ws;        // 128*4096 = 524288 shorts
  short* fw1s = wcb + 524288;        // 16384
  short* fw2s = fw1s + 16384;        // 131072
  short* fw3s = fw2s + 131072;       // 8192
  short* hw1b = fw3s + 8192;         // 8192

  hipLaunchKernelGGL(k0_prep, dim3(640), dim3(256), 0, stream,
                     fw1, fw2, fw3, hw1, fw1s, fw2s, fw3s, hw1b);
  hipLaunchKernelGGL(k1_wcb, dim3(128), dim3(256), 0, stream, psi, dw, wcb);
  hipLaunchKernelGGL(k2_disco_mfma, dim3(8, 128, 2), dim3(256), 0, stream,
                     x, wcb, db, hw1b, hb1, hw2, hb2, outb);
  hipLaunchKernelGGL(k3_mfma, dim3(2048), dim3(256), 0, stream,
                     fw1s, fw2s, fw3s, fb1, fb2, fb3, outb);
}

// Round 5
// 202.825 us; speedup vs baseline: 4.8295x; 1.0901x over previous
//
#include <hip/hip_runtime.h>
#include <math.h>

// Problem constants
// B=2, H=128, W=256, MD=34, LD=32, NH=4, HD=8, SH=64, K=25, P=7, R=3,
// FF1=512, FF2=256

typedef __attribute__((ext_vector_type(8))) short bfrag;    // 8 bf16 = 4 VGPR
typedef __attribute__((ext_vector_type(4))) float ffrag;    // 4 f32 acc

union bfi4 { int4 i; bfrag b; };

// Fast tanh-form GELU (~8 VALU ops, |err| vs erf-GELU ~3e-3)
__device__ __forceinline__ float gelu_f(float v) {
  const float z = v * (1.5957691216f + 0.0713548163f * v * v);
  const float e = __expf(-z);
  return v * __builtin_amdgcn_rcpf(1.0f + e);
}

// exact RNE (cold paths: weight prep)
__device__ __forceinline__ short f2bf(float f) {
  union { float f; unsigned u; } v; v.f = f;
  unsigned r = (v.u + 0x7fffu + ((v.u >> 16) & 1u)) >> 16;
  return (short)r;
}

// round-half-up (2 VALU ops)
__device__ __forceinline__ short f2bf_fast(float f) {
  union { float f; unsigned u; } v; v.f = f;
  return (short)((v.u + 0x8000u) >> 16);
}

// pack two f32 -> bf16 pair in one dword: (bf(b)<<16)|bf(a); 3 VALU ops
__device__ __forceinline__ int pkbf(float a, float b) {
  union { float f; unsigned u; } va, vb; va.f = a; vb.f = b;
  return (int)__builtin_amdgcn_perm(vb.u + 0x8000u, va.u + 0x8000u, 0x07060302u);
}

// DPP cross-lane add: v += lane-permuted v. Reduction over 16 lanes =
// xor1 (quad_perm 1,0,3,2), xor2 (quad_perm 2,3,0,1), then half-mirror /
// mirror (valid as xor4/xor8 once quads hold equal partial sums).
template <int CTRL>
__device__ __forceinline__ float dpp_add(float v) {
  union { float f; int i; } s, t;
  s.f = v;
  t.i = __builtin_amdgcn_update_dpp(0, s.i, CTRL, 0xf, 0xf, true);
  return v + t.f;
}
__device__ __forceinline__ float reduce16(float v) {
  v = dpp_add<0xB1>(v);    // quad_perm [1,0,3,2]  = xor1
  v = dpp_add<0x4E>(v);    // quad_perm [2,3,0,1]  = xor2
  v = dpp_add<0x141>(v);   // row_half_mirror      ~ xor4 after fold
  v = dpp_add<0x140>(v);   // row_mirror           ~ xor8 after fold
  return v;
}

// ---------------------------------------------------------------------------
// K0: swizzle fw1/fw2/fw3 (k3) and hw1 (k2) into bf16 MFMA B-fragments.
// B-frag (16x16x32): lane holds B[k][n], n=lane&15, k=(lane>>4)*8+j.
// hw1b uses slot-relabeled K: slot s <-> f_orig = (s&3)*16 + (s>>2).
// ---------------------------------------------------------------------------
__global__ __launch_bounds__(256) void k0_prep(
    const float* __restrict__ fw1, const float* __restrict__ fw2,
    const float* __restrict__ fw3, const float* __restrict__ hw1,
    short* __restrict__ fw1s, short* __restrict__ fw2s,
    short* __restrict__ fw3s, short* __restrict__ hw1b) {
  const int e = blockIdx.x * 256 + threadIdx.x;
  if (e < 16384) {                       // fw1: K=32 (1 kt), N=512 (32 nt)
    const int j = e & 7, lane = (e >> 3) & 63, nt = e >> 9;
    const int k = (lane >> 4) * 8 + j, n = nt * 16 + (lane & 15);
    fw1s[e] = f2bf(fw1[k * 512 + n]);
  } else if (e < 16384 + 131072) {       // fw2: K=512 (16 kt), N=256 (16 nt)
    const int e2 = e - 16384;
    const int j = e2 & 7, lane = (e2 >> 3) & 63;
    const int nt = (e2 >> 9) & 15, kt = e2 >> 13;
    const int k = kt * 32 + (lane >> 4) * 8 + j, n = nt * 16 + (lane & 15);
    fw2s[e2] = f2bf(fw2[k * 256 + n]);
  } else if (e < 16384 + 131072 + 8192) { // fw3: K=256 (8 kt), N=32 (2 nt)
    const int e3 = e - 147456;
    const int j = e3 & 7, lane = (e3 >> 3) & 63;
    const int nt = (e3 >> 9) & 1, kt = e3 >> 10;
    const int k = kt * 32 + (lane >> 4) * 8 + j, n = nt * 16 + (lane & 15);
    fw3s[e3] = f2bf(fw3[k * 32 + n]);
  } else if (e < 163840) {               // hw1: per head, slot-K, N=32 (2 nt)
    const int e4 = e - 155648;
    const int jj = e4 & 7, lane = (e4 >> 3) & 63;
    const int fr = (e4 >> 9) & 3, n = e4 >> 11;    // fr = kt*2+nt
    const int kt = fr >> 1, nt = fr & 1;
    const int s = kt * 32 + (lane >> 4) * 8 + jj;  // slot index
    const int forig = (s & 3) * 16 + (s >> 2);     // slot -> original f
    const int o = nt * 16 + (lane & 15);
    hw1b[e4] = f2bf(hw1[n * 2048 + forig * 32 + o]);
  }
}

// ---------------------------------------------------------------------------
// K1: conv weights as bf16 B-fragments per latitude, TWO j-phase sets.
// wcb[h][((par*2+kt)*4+nt)*512 + lane*8 + jj]:
//   k = kt*32+(lane>>4)*8+jj -> r=k>>3, dlt=k&7; f = nt*16+(lane&15)
//   par=0 (even pixels): tap j = dlt   (0 if r==7 or dlt==7)
//   par=1 (odd pixels):  tap j = dlt-1 (0 if r==7 or dlt==0)
// ---------------------------------------------------------------------------
__global__ __launch_bounds__(256) void k1_wcb(
    const float* __restrict__ psi, const float* __restrict__ dw,
    short* __restrict__ wcb) {
  __shared__ float psiL[25 * 49];
  const int h = blockIdx.x;
  for (int e = threadIdx.x; e < 1225; e += 256)
    psiL[e] = psi[(e / 49) * (128 * 49) + h * 49 + (e % 49)];
  __syncthreads();
  short* outp = wcb + h * 8192;
  for (int idx = threadIdx.x; idx < 8192; idx += 256) {
    const int jj = idx & 7, lane = (idx >> 3) & 63;
    const int nt = (idx >> 9) & 3, kt = (idx >> 11) & 1, par = idx >> 12;
    const int k = kt * 32 + (lane >> 4) * 8 + jj;
    const int f = nt * 16 + (lane & 15);
    const int r = k >> 3, dlt = k & 7;
    const int j = par ? (dlt - 1) : dlt;
    float acc = 0.f;
    if (r < 7 && j >= 0 && j < 7) {
      const int p = r * 7 + j;
#pragma unroll
      for (int kk = 0; kk < 25; ++kk)
        acc += dw[f * 25 + kk] * psiL[kk * 49 + p];
    }
    outp[idx] = f2bf(acc);
  }
}

// ---------------------------------------------------------------------------
// K2: DISCO conv + head MLP via MFMA; DS-minimized.
// grid (8,128,2), block 256 (4 waves), wave == head.
// Per c (8 per wave): one tap A-frag pair serves BOTH pixel parities
// (ds_read2_b32-friendly dword gathers); conv d -> sD in slot layout
// (b64 writes / b128 reads); MLP2 reduced with DPP (no LDS).
// ---------------------------------------------------------------------------
__global__ __launch_bounds__(256, 3) void k2_disco_mfma(
    const float* __restrict__ x,   const short* __restrict__ wcb,
    const float* __restrict__ db,  const short* __restrict__ hw1b,
    const float* __restrict__ hb1, const float* __restrict__ hw2,
    const float* __restrict__ hb2, float* __restrict__ outb) {
  // sX: [c][r 0..7][wp 0..47], c-stride 388 shorts (194 dw == 2 mod 32:
  // stage-write 2-way only), r-stride 48. Row r=7 and wp>=39 stay zero.
  __shared__ __align__(16) short sX[32 * 388];       // 24832 B
  // per-wave d tile [m 16][slot 64 pad 72]: slot = lm*4+nt -> b64 writes,
  // b128 reads (row stride 144 B = 16B-aligned).
  __shared__ __align__(16) short sD[4][16 * 72];     //  9216 B

  const int tid = threadIdx.x;
  const int w0  = blockIdx.x * 32;
  const int h   = blockIdx.y;
  const int b   = blockIdx.z;

  {  // zero-fill sX (pads must be 0.0bf16, never garbage)
    int4* p = (int4*)sX;
    int4 z; z.x = z.y = z.z = z.w = 0;
    for (int e = tid; e < (32 * 388) / 8; e += 256) p[e] = z;
  }
  __syncthreads();

  // stage x tile as bf16 (float2 over c-pairs)
  for (int e = tid; e < 7 * 39 * 16; e += 256) {
    const int c2 = e & 15, t = e >> 4;
    const int wp = t % 39, r = t / 39;
    int hr = h - 3 + r; hr = hr < 0 ? 0 : (hr > 127 ? 127 : hr);
    const int wr = (w0 - 3 + wp) & 255;
    const float2 v = *(const float2*)&x[((b * 128 + hr) * 256 + wr) * 34 + c2 * 2];
    short* dp = &sX[(c2 * 2) * 388 + r * 48 + wp];
    dp[0]   = f2bf_fast(v.x);
    dp[388] = f2bf_fast(v.y);
  }
  __syncthreads();

  const int lane = tid & 63, lm = lane & 15, lq = lane >> 4;
  const int n = tid >> 6;  // wave == head

  float dbv[4];
#pragma unroll
  for (int nt = 0; nt < 4; ++nt) dbv[nt] = db[nt * 16 + lm];
  float hb1v[2], hw2v[2];
#pragma unroll
  for (int nt = 0; nt < 2; ++nt) {
    hb1v[nt] = hb1[n * 32 + nt * 16 + lm];
    hw2v[nt] = hw2[n * 32 + nt * 16 + lm];
  }
  const float hb2n = hb2[n];

  // conv B-frags: [par][kt][nt] (block-uniform per h; L2-hot)
  bfrag cB[2][2][4];
#pragma unroll
  for (int par = 0; par < 2; ++par)
#pragma unroll
    for (int kt = 0; kt < 2; ++kt)
#pragma unroll
      for (int nt = 0; nt < 4; ++nt)
        cB[par][kt][nt] = *(const bfrag*)(wcb + h * 8192 +
                            ((par * 2 + kt) * 4 + nt) * 512 + lane * 8);
  // MLP1 B-frags (slot-K): [kt][nt]
  bfrag mB[2][2];
#pragma unroll
  for (int kt = 0; kt < 2; ++kt)
#pragma unroll
    for (int nt = 0; nt < 2; ++nt)
      mB[kt][nt] = *(const bfrag*)(hw1b + n * 2048 + (kt * 2 + nt) * 512 + lane * 8);

  short* sDw = (short*)sD[n];
  const int* tpB = (const int*)sX;

#pragma unroll 1
  for (int i = 0; i < 8; ++i) {
    const int c = n * 8 + i;

    // tap A-frags (shared by both parities): dword-aligned gathers.
    // lane lm <-> pixel-pair base 2*lm; kt0: r=lq, kt1: r=4+lq.
    const int base0 = c * 194 + lq * 24 + lm;
    bfi4 u0, u1;
    u0.i.x = tpB[base0];      u0.i.y = tpB[base0 + 1];
    u0.i.z = tpB[base0 + 2];  u0.i.w = tpB[base0 + 3];
    u1.i.x = tpB[base0 + 96]; u1.i.y = tpB[base0 + 97];
    u1.i.z = tpB[base0 + 98]; u1.i.w = tpB[base0 + 99];

#pragma unroll
    for (int par = 0; par < 2; ++par) {
      ffrag dacc[4];
#pragma unroll
      for (int nt = 0; nt < 4; ++nt) dacc[nt] = ffrag{0.f, 0.f, 0.f, 0.f};
#pragma unroll
      for (int nt = 0; nt < 4; ++nt) {
        dacc[nt] = __builtin_amdgcn_mfma_f32_16x16x32_bf16(u0.b, cB[par][0][nt], dacc[nt], 0, 0, 0);
        dacc[nt] = __builtin_amdgcn_mfma_f32_16x16x32_bf16(u1.b, cB[par][1][nt], dacc[nt], 0, 0, 0);
      }

      // d -> sD: row = conv m (lq*4+rr), slots lm*4+nt packed -> one b64/row
#pragma unroll
      for (int rr = 0; rr < 4; ++rr) {
        int2 w;
        w.x = pkbf(dacc[0][rr] + dbv[0], dacc[1][rr] + dbv[1]);
        w.y = pkbf(dacc[2][rr] + dbv[2], dacc[3][rr] + dbv[3]);
        *(int2*)(sDw + (lq * 4 + rr) * 72 + lm * 4) = w;
      }
      // same-wave DS ordering -> no barrier

      // MLP1 A-frags: row m = lm, k-slots kt*32 + lq*8 + (0..7): one b128 each
      bfrag a1[2];
#pragma unroll
      for (int kt = 0; kt < 2; ++kt)
        a1[kt] = *(const bfrag*)(sDw + lm * 72 + kt * 32 + lq * 8);

      ffrag h1[2];
      h1[0] = ffrag{0.f, 0.f, 0.f, 0.f};
      h1[1] = ffrag{0.f, 0.f, 0.f, 0.f};
#pragma unroll
      for (int nt = 0; nt < 2; ++nt) {
        h1[nt] = __builtin_amdgcn_mfma_f32_16x16x32_bf16(a1[0], mB[0][nt], h1[nt], 0, 0, 0);
        h1[nt] = __builtin_amdgcn_mfma_f32_16x16x32_bf16(a1[1], mB[1][nt], h1[nt], 0, 0, 0);
      }

      // MLP2: gelu + hw2 dot, reduce over the 16 o-lanes with DPP
      float vsum[4];
#pragma unroll
      for (int rr = 0; rr < 4; ++rr) {
        float v = gelu_f(h1[0][rr] + hb1v[0]) * hw2v[0] +
                  gelu_f(h1[1][rr] + hb1v[1]) * hw2v[1];
        vsum[rr] = reduce16(v);
      }

      if (lm == 0) {
#pragma unroll
        for (int rr = 0; rr < 4; ++rr) {
          const int p = 2 * (lq * 4 + rr) + par;
          const int idx = ((b * 128 + h) * 256 + (w0 + p)) * 34 + c;
          outb[idx] = vsum[rr] + hb2n + x[idx];   // exact fp32 residual
        }
      }
    }
  }

  // sincos passthrough
  if (tid < 64) {
    const int wl = tid >> 1;
    const int sc = tid & 1;
    const int idx = ((b * 128 + h) * 256 + (w0 + wl)) * 34 + 32 + sc;
    outb[idx] = x[idx];
  }
}

// ---------------------------------------------------------------------------
// K3: fused MLP 32 -> 512(gelu) -> 256(gelu) -> 32 (+residual), bf16 MFMA,
// with explicit B-frag prefetch (L2 loop) and hoisted weight/residual loads.
// ---------------------------------------------------------------------------
__global__ __launch_bounds__(256, 3) void k3_mfma(
    const short* __restrict__ fw1s, const short* __restrict__ fw2s,
    const short* __restrict__ fw3s,
    const float* __restrict__ fb1, const float* __restrict__ fb2,
    const float* __restrict__ fb3, float* __restrict__ outb) {
  __shared__ short sT1[32 * 520];   // 33280 B
  __shared__ short sT2[32 * 264];   // 16896 B

  const int tid  = threadIdx.x;
  const int lane = tid & 63;
  const int wave = tid >> 6;
  const int pix0 = blockIdx.x * 32;
  const int lm   = lane & 15;
  const int lq   = lane >> 4;
  const int koff = lq * 8;

  const int mt3 = wave & 1;
  const int nt3 = wave >> 1;
  const int col3 = nt3 * 16 + lm;

  // ---- hoisted loads: x_mid A-frags, fw1 B-frags, fw3 B-frags, residuals
  bfrag aF[2];
#pragma unroll
  for (int mt = 0; mt < 2; ++mt) {
    const float* ap = outb + (pix0 + mt * 16 + lm) * 34 + koff;
    float2 v0 = *(const float2*)(ap + 0);
    float2 v1 = *(const float2*)(ap + 2);
    float2 v2 = *(const float2*)(ap + 4);
    float2 v3 = *(const float2*)(ap + 6);
    bfrag a;
    a[0] = f2bf_fast(v0.x); a[1] = f2bf_fast(v0.y);
    a[2] = f2bf_fast(v1.x); a[3] = f2bf_fast(v1.y);
    a[4] = f2bf_fast(v2.x); a[5] = f2bf_fast(v2.y);
    a[6] = f2bf_fast(v3.x); a[7] = f2bf_fast(v3.y);
    aF[mt] = a;
  }
  bfrag b1f[8];
#pragma unroll
  for (int ni = 0; ni < 8; ++ni)
    b1f[ni] = *(const bfrag*)(fw1s + (wave * 8 + ni) * 512 + lane * 8);
  bfrag w3f[8];
#pragma unroll
  for (int kt = 0; kt < 8; ++kt)
    w3f[kt] = *(const bfrag*)(fw3s + nt3 * 512 + kt * 1024 + lane * 8);
  float res3[4];
#pragma unroll
  for (int r = 0; r < 4; ++r)
    res3[r] = outb[(pix0 + mt3 * 16 + lq * 4 + r) * 34 + col3];

  // ---- layer 1
#pragma unroll
  for (int ni = 0; ni < 8; ++ni) {
    const int nt = wave * 8 + ni;
#pragma unroll
    for (int mt = 0; mt < 2; ++mt) {
      ffrag c = {0.f, 0.f, 0.f, 0.f};
      c = __builtin_amdgcn_mfma_f32_16x16x32_bf16(aF[mt], b1f[ni], c, 0, 0, 0);
      const int col = nt * 16 + lm;
      const float bias = fb1[col];
#pragma unroll
      for (int r = 0; r < 4; ++r) {
        const int row = mt * 16 + lq * 4 + r;
        sT1[row * 520 + col] = f2bf_fast(gelu_f(c[r] + bias));
      }
    }
  }
  __syncthreads();

  // ---- layer 2 with distance-1 B prefetch
  const int n0 = wave * 4;
  ffrag acc[2][4];
#pragma unroll
  for (int mt = 0; mt < 2; ++mt)
#pragma unroll
    for (int ni = 0; ni < 4; ++ni) acc[mt][ni] = ffrag{0.f, 0.f, 0.f, 0.f};

  const short* sA0 = &sT1[lm * 520 + koff];
  const short* sA1 = sA0 + 16 * 520;
  const short* w2p = fw2s + n0 * 512 + lane * 8;

  bfrag bv[4];
#pragma unroll
  for (int ni = 0; ni < 4; ++ni)
    bv[ni] = *(const bfrag*)(w2p + ni * 512);

#pragma unroll 2
  for (int kt = 0; kt < 16; ++kt) {
    bfrag bnext[4];
    if (kt < 15) {
#pragma unroll
      for (int ni = 0; ni < 4; ++ni)
        bnext[ni] = *(const bfrag*)(w2p + (kt + 1) * 8192 + ni * 512);
    }
    const bfrag a0 = *(const bfrag*)(sA0 + kt * 32);
    const bfrag a1 = *(const bfrag*)(sA1 + kt * 32);
#pragma unroll
    for (int ni = 0; ni < 4; ++ni) {
      acc[0][ni] = __builtin_amdgcn_mfma_f32_16x16x32_bf16(a0, bv[ni], acc[0][ni], 0, 0, 0);
      acc[1][ni] = __builtin_amdgcn_mfma_f32_16x16x32_bf16(a1, bv[ni], acc[1][ni], 0, 0, 0);
    }
    if (kt < 15) {
#pragma unroll
      for (int ni = 0; ni < 4; ++ni) bv[ni] = bnext[ni];
    }
  }
#pragma unroll
  for (int mt = 0; mt < 2; ++mt)
#pragma unroll
    for (int ni = 0; ni < 4; ++ni) {
      const int col = (n0 + ni) * 16 + lm;
      const float bias = fb2[col];
#pragma unroll
      for (int r = 0; r < 4; ++r) {
        const int row = mt * 16 + lq * 4 + r;
        sT2[row * 264 + col] = f2bf_fast(gelu_f(acc[mt][ni][r] + bias));
      }
    }
  __syncthreads();

  // ---- layer 3 (weights already in w3f, residuals in res3)
  ffrag c3 = {0.f, 0.f, 0.f, 0.f};
  const short* sA3 = &sT2[(mt3 * 16 + lm) * 264 + koff];
#pragma unroll
  for (int kt = 0; kt < 8; ++kt) {
    const bfrag a = *(const bfrag*)(sA3 + kt * 32);
    c3 = __builtin_amdgcn_mfma_f32_16x16x32_bf16(a, w3f[kt], c3, 0, 0, 0);
  }
  {
    const float bias = fb3[col3];
#pragma unroll
    for (int r = 0; r < 4; ++r) {
      const int row = mt3 * 16 + lq * 4 + r;
      outb[(pix0 + row) * 34 + col3] = c3[r] + bias + res3[r];
    }
  }
}

// ---------------------------------------------------------------------------
extern "C" void kernel_launch(void* const* d_in, const int* in_sizes, int n_in,
                              void* d_out, int out_size, void* d_ws, size_t ws_size,
                              hipStream_t stream) {
  const float* x   = (const float*)d_in[0];
  const float* psi = (const float*)d_in[1];
  const float* dw  = (const float*)d_in[2];
  const float* db  = (const float*)d_in[3];
  const float* hw1 = (const float*)d_in[4];
  const float* hb1 = (const float*)d_in[5];
  const float* hw2 = (const float*)d_in[6];
  const float* hb2 = (const float*)d_in[7];
  const float* fw1 = (const float*)d_in[8];
  const float* fb1 = (const float*)d_in[9];
  const float* fw2 = (const float*)d_in[10];
  const float* fb2 = (const float*)d_in[11];
  const float* fw3 = (const float*)d_in[12];
  const float* fb3 = (const float*)d_in[13];
  float* outb = (float*)d_out;

  // workspace: wcb 2 MB + swizzled weights (~0.33 MB)
  short* wcb  = (short*)d_ws;        // 128*8192 = 1048576 shorts
  short* fw1s = wcb + 1048576;       // 16384
  short* fw2s = fw1s + 16384;        // 131072
  short* fw3s = fw2s + 131072;       // 8192
  short* hw1b = fw3s + 8192;         // 8192

  hipLaunchKernelGGL(k0_prep, dim3(640), dim3(256), 0, stream,
                     fw1, fw2, fw3, hw1, fw1s, fw2s, fw3s, hw1b);
  hipLaunchKernelGGL(k1_wcb, dim3(128), dim3(256), 0, stream, psi, dw, wcb);
  hipLaunchKernelGGL(k2_disco_mfma, dim3(8, 128, 2), dim3(256), 0, stream,
                     x, wcb, db, hw1b, hb1, hw2, hb2, outb);
  hipLaunchKernelGGL(k3_mfma, dim3(2048), dim3(256), 0, stream,
                     fw1s, fw2s, fw3s, fb1, fb2, fb3, outb);
}